// Round 3
// baseline (491.958 us; speedup 1.0000x reference)
//
#include <hip/hip_runtime.h>

#define B_    1024
#define NG_   32
#define F_    16
#define ED_   6
#define EG_   256
#define ET_   262144
#define H1_   5
#define C1_   80
#define HC1_  400
#define C2_   160
#define OBS_  512

#define S1_   408   // bf16 element stride for 400-wide node rows (816B, 16B-aligned)
#define MSG_S 161

typedef unsigned short ushort8v __attribute__((ext_vector_type(8)));

__device__ __forceinline__ float bf2f(unsigned short u) {
  return __uint_as_float(((unsigned int)u) << 16);
}
__device__ __forceinline__ unsigned short f2bf(float f) {
  unsigned int u = __float_as_uint(f);
  u = u + 0x7FFFu + ((u >> 16) & 1u);   // RNE
  return (unsigned short)(u >> 16);
}
__device__ __forceinline__ float dot8(ushort8v hv, float4 wa, float4 wb, float acc) {
  acc = fmaf(bf2f(hv[0]), wa.x, acc);
  acc = fmaf(bf2f(hv[1]), wa.y, acc);
  acc = fmaf(bf2f(hv[2]), wa.z, acc);
  acc = fmaf(bf2f(hv[3]), wa.w, acc);
  acc = fmaf(bf2f(hv[4]), wb.x, acc);
  acc = fmaf(bf2f(hv[5]), wb.y, acc);
  acc = fmaf(bf2f(hv[6]), wb.z, acc);
  acc = fmaf(bf2f(hv[7]), wb.w, acc);
  return acc;
}

// ---------------------------------------------------------------------------
// Kernel A: one block (512 threads) per graph.
// ---------------------------------------------------------------------------
__global__ __launch_bounds__(512, 2)
void gnn_two_layer_kernel(
    const float* __restrict__ x, const int* __restrict__ eidx,
    const float* __restrict__ eattr,
    const float* __restrict__ Wl1, const float* __restrict__ bl1,
    const float* __restrict__ Wr1, const float* __restrict__ br1,
    const float* __restrict__ We1, const float* __restrict__ att1,
    const float* __restrict__ bc1,
    const float* __restrict__ Wl2, const float* __restrict__ bl2,
    const float* __restrict__ Wr2, const float* __restrict__ br2,
    const float* __restrict__ We2, const float* __restrict__ att2,
    const float* __restrict__ bc2,
    float* __restrict__ egoH)
{
  __shared__ unsigned short xl[NG_ * S1_];    // layer-1 source transform (message), bf16
  __shared__ unsigned short xrh[NG_ * S1_];   // layer-1 target transform, then reused as h
  __shared__ float sc[EG_ * H1_];             // scores -> alpha
  __shared__ float ea[EG_ * ED_];
  __shared__ int   esrc[EG_], edst[EG_];
  __shared__ int   eorder[EG_];
  __shared__ int   bstart[NG_ + 1];
  __shared__ float msg[8 * MSG_S];
  __shared__ float out2[C2_], xr2v[C2_];
  __shared__ float sArr[8], wArr[8];
  __shared__ float mrun_s, denrun_s, scale_s;

  const int b   = blockIdx.x;
  const int tid = threadIdx.x;
  const int n0  = b * NG_;
  const int eb  = b * EG_;

  // ---------------- phase 1: loads ----------------
  if (tid < EG_) {
    esrc[tid] = eidx[eb + tid] - n0;
    edst[tid] = eidx[ET_ + eb + tid] - n0;
  }
  for (int i = tid; i < EG_ * ED_; i += 512) ea[i] = eattr[eb * ED_ + i];
  __syncthreads();

  // ---------------- phase 2: node transforms ----------------
  {
    const int n = tid & 31;
    const float* xrow = &x[(n0 + n) * F_];
    float xv[16];
#pragma unroll
    for (int q = 0; q < 4; ++q) {
      float4 t = *(const float4*)(xrow + q * 4);
      xv[q*4+0] = t.x; xv[q*4+1] = t.y; xv[q*4+2] = t.z; xv[q*4+3] = t.w;
    }
    for (int o = (tid >> 5); o < 50; o += 16) {   // 50 octs of 8 channels
      const int c = o * 8;
      ushort8v hl, hr;
#pragma unroll
      for (int u = 0; u < 8; ++u) {
        const int cc = c + u;
        float aL = bl1[cc], aR = br1[cc];
        const float* wl = &Wl1[cc * F_];
        const float* wr = &Wr1[cc * F_];
#pragma unroll
        for (int k = 0; k < 16; ++k) {
          aL = fmaf(xv[k], wl[k], aL);
          aR = fmaf(xv[k], wr[k], aR);
        }
        hl[u] = f2bf(aL);
        hr[u] = f2bf(aR);
      }
      *(ushort8v*)(&xl[n * S1_ + c])  = hl;
      *(ushort8v*)(&xrh[n * S1_ + c]) = hr;
    }
  }
  __syncthreads();

  // ---------------- phase 3: edge scores ----------------
  // thread = (edge, channel-half). s is wave-uniform (readfirstlane) so all
  // We1/att1 addresses stay SGPR-uniform -> s_load, not per-lane vector loads.
  {
    const int e = tid & 255;
    const int s = __builtin_amdgcn_readfirstlane((int)(threadIdx.x >> 8) & 1);
    const int sl = esrc[e], dl = edst[e];
    const float e0 = ea[e*ED_+0], e1 = ea[e*ED_+1], e2 = ea[e*ED_+2];
    const float e3 = ea[e*ED_+3], e4 = ea[e*ED_+4], e5 = ea[e*ED_+5];
    const unsigned short* xlrow = &xl[sl * S1_ + s * 40];
    const unsigned short* xrrow = &xrh[dl * S1_ + s * 40];
    float part[H1_];
#pragma unroll
    for (int h = 0; h < H1_; ++h) {
      float sh = 0.f;
#pragma unroll
      for (int co = 0; co < 5; ++co) {
        const int cbase = h * C1_ + s * 40 + co * 8;     // uniform (s in SGPR)
        ushort8v av = *(const ushort8v*)(xlrow + h * C1_ + co * 8);
        ushort8v rv = *(const ushort8v*)(xrrow + h * C1_ + co * 8);
#pragma unroll
        for (int u = 0; u < 8; ++u) {
          const float* wv6 = &We1[(cbase + u) * ED_];
          float t0 = fmaf(wv6[1], e1, wv6[0] * e0);
          float t1 = fmaf(wv6[3], e3, wv6[2] * e2);
          float t2 = fmaf(wv6[5], e5, wv6[4] * e4);
          float p = (bf2f(av[u]) + bf2f(rv[u])) + (t0 + (t1 + t2));
          p = fmaxf(p, 0.2f * p);                         // leaky_relu
          sh = fmaf(p, att1[cbase + u], sh);
        }
      }
      part[h] = sh;
    }
    if (s == 0) {
#pragma unroll
      for (int h = 0; h < H1_; ++h) sc[e * H1_ + h] = part[h];
    }
    __syncthreads();
    if (s == 1) {
#pragma unroll
      for (int h = 0; h < H1_; ++h) sc[e * H1_ + h] += part[h];
    }
  }
  __syncthreads();

  // ---------------- phase 4: deterministic buckets by dst ----------------
  if (tid < NG_) {
    int cnt = 0;
    for (int e = 0; e < EG_; ++e) cnt += (edst[e] == tid);
    bstart[tid + 1] = cnt;
  }
  __syncthreads();
  if (tid == 0) {
    bstart[0] = 0;
    for (int d = 0; d < NG_; ++d) bstart[d + 1] += bstart[d];
  }
  __syncthreads();
  if (tid < NG_) {
    int p = bstart[tid];
    for (int e = 0; e < EG_; ++e)
      if (edst[e] == tid) eorder[p++] = e;
  }
  __syncthreads();

  // ---------------- phase 5: segment softmax per (dst, head) ----------------
  if (tid < NG_ * H1_) {
    const int d = tid & 31, h = tid >> 5;
    const int s0 = bstart[d], s1 = bstart[d + 1];
    float m = -INFINITY;
    for (int k = s0; k < s1; ++k) m = fmaxf(m, sc[eorder[k] * H1_ + h]);
    float den = 0.f;
    for (int k = s0; k < s1; ++k) {
      float t = expf(sc[eorder[k] * H1_ + h] - m);
      den += t;
      sc[eorder[k] * H1_ + h] = t;
    }
    const float r = 1.f / (den + 1e-16f);
    for (int k = s0; k < s1; ++k) sc[eorder[k] * H1_ + h] *= r;
  }
  __syncthreads();

  // ---------------- phase 6: aggregation, h = relu(sum alpha*msg + bc1) -----
  for (int idx = tid; idx < NG_ * 50; idx += 512) {
    const int d  = idx / 50;
    const int co = idx - d * 50;
    const int c  = co * 8;
    const int h  = c / C1_;           // oct never crosses a head (8 | 80)
    const int s0 = bstart[d], s1 = bstart[d + 1];
    float acc[8] = {0.f,0.f,0.f,0.f,0.f,0.f,0.f,0.f};
    for (int k = s0; k < s1; ++k) {
      const int e = eorder[k];
      const float al = sc[e * H1_ + h];
      ushort8v xv = *(const ushort8v*)(&xl[esrc[e] * S1_ + c]);
#pragma unroll
      for (int u = 0; u < 8; ++u) acc[u] = fmaf(al, bf2f(xv[u]), acc[u]);
    }
    ushort8v hv;
#pragma unroll
    for (int u = 0; u < 8; ++u)
      hv[u] = f2bf(fmaxf(acc[u] + bc1[c + u], 0.f));
    *(ushort8v*)(&xrh[d * S1_ + c]) = hv;   // xr dead; reuse as h
  }
  __syncthreads();

  // ---------------- phase 7: layer-2, ego node only ----------------
  const int nE = bstart[1];   // edges with local dst == 0
  const int wv = tid >> 6;    // wave id 0..7  -> cc range [wv*20, wv*20+20)
  const int ln = tid & 63;
  const int qq = ln >> 3;     // k-part 0..7
  const int jv = ln & 7;      // edge slot 0..7

  // xr2v[cc] = Wr2[cc] . h[ego] + br2[cc]  — wave GEMM, coalesced row reads
  for (int p = 0; p < 10; ++p) {
    const int cc0 = wv * 20 + p * 2;
    float a0 = 0.f, a1 = 0.f;
    if (ln < 50) {
      const int k = ln * 8;
      ushort8v hv = *(const ushort8v*)(&xrh[k]);          // ego row
      const float* w0 = &Wr2[cc0 * HC1_ + k];
      const float* w1 = w0 + HC1_;
      a0 = dot8(hv, *(const float4*)w0, *(const float4*)(w0 + 4), a0);
      a1 = dot8(hv, *(const float4*)w1, *(const float4*)(w1 + 4), a1);
    }
#pragma unroll
    for (int d = 1; d < 64; d <<= 1) {
      a0 += __shfl_xor(a0, d);
      a1 += __shfl_xor(a1, d);
    }
    if (ln == 0) {
      xr2v[cc0]     = a0 + br2[cc0];
      xr2v[cc0 + 1] = a1 + br2[cc0 + 1];
    }
  }
  if (tid < C2_) out2[tid] = 0.f;
  if (tid == 0) { mrun_s = -INFINITY; denrun_s = 0.f; scale_s = 0.f; }

  for (int ch = 0; ch < nE; ch += 8) {
    const int nc = min(8, nE - ch);
    // msg[j][cc] = Wl2[cc] . h[src_j] + bl2[cc] — wave GEMM:
    // lane = (q=k-part, j=edge); Wl2 row read once per block, 8-way broadcast.
    const int jj = (jv < nc) ? jv : 0;
    const int srcRow = esrc[eorder[ch + jj]] * S1_;
    for (int p = 0; p < 10; ++p) {
      const int cc0 = wv * 20 + p * 2;
      const float* wr0 = &Wl2[cc0 * HC1_];
      const float* wr1 = wr0 + HC1_;
      float a0 = 0.f, a1 = 0.f;
#pragma unroll
      for (int i = 0; i < 6; ++i) {
        const int k = qq * 8 + i * 64;                    // covers 0..383
        ushort8v hv = *(const ushort8v*)(&xrh[srcRow + k]);
        a0 = dot8(hv, *(const float4*)(wr0 + k), *(const float4*)(wr0 + k + 4), a0);
        a1 = dot8(hv, *(const float4*)(wr1 + k), *(const float4*)(wr1 + k + 4), a1);
      }
      if (qq < 2) {                                       // tail k = 384, 392
        const int k = 384 + qq * 8;
        ushort8v hv = *(const ushort8v*)(&xrh[srcRow + k]);
        a0 = dot8(hv, *(const float4*)(wr0 + k), *(const float4*)(wr0 + k + 4), a0);
        a1 = dot8(hv, *(const float4*)(wr1 + k), *(const float4*)(wr1 + k + 4), a1);
      }
      a0 += __shfl_xor(a0, 8); a0 += __shfl_xor(a0, 16); a0 += __shfl_xor(a0, 32);
      a1 += __shfl_xor(a1, 8); a1 += __shfl_xor(a1, 16); a1 += __shfl_xor(a1, 32);
      if (ln < 8) {
        msg[jv * MSG_S + cc0]     = a0 + bl2[cc0];
        msg[jv * MSG_S + cc0 + 1] = a1 + bl2[cc0 + 1];
      }
    }
    __syncthreads();
    if (tid < nc) {
      const int e = eorder[ch + tid];
      const float e0 = ea[e*ED_+0], e1 = ea[e*ED_+1], e2 = ea[e*ED_+2];
      const float e3 = ea[e*ED_+3], e4 = ea[e*ED_+4], e5 = ea[e*ED_+5];
      float s = 0.f;
      for (int cc = 0; cc < C2_; ++cc) {
        const float* wv6 = &We2[cc * ED_];
        float t0 = fmaf(wv6[1], e1, wv6[0] * e0);
        float t1 = fmaf(wv6[3], e3, wv6[2] * e2);
        float t2 = fmaf(wv6[5], e5, wv6[4] * e4);
        float p = msg[tid * MSG_S + cc] + xr2v[cc] + (t0 + (t1 + t2));
        p = fmaxf(p, 0.2f * p);
        s = fmaf(p, att2[cc], s);
      }
      sArr[tid] = s;
    }
    __syncthreads();
    if (tid == 0) {
      float m = mrun_s;
      for (int j = 0; j < nc; ++j) m = fmaxf(m, sArr[j]);
      const float scl = expf(mrun_s - m);    // expf(-inf)=0 on first chunk
      float den = denrun_s * scl;
      for (int j = 0; j < nc; ++j) { float w = expf(sArr[j] - m); wArr[j] = w; den += w; }
      mrun_s = m; denrun_s = den; scale_s = scl;
    }
    __syncthreads();
    if (tid < C2_) {
      float o = out2[tid] * scale_s;
      for (int j = 0; j < nc; ++j) o = fmaf(wArr[j], msg[j * MSG_S + tid], o);
      out2[tid] = o;
    }
    __syncthreads();
  }

  if (tid < C2_) {
    const float v = out2[tid] / (denrun_s + 1e-16f) + bc2[tid];
    egoH[b * C2_ + tid] = fmaxf(v, 0.f);
  }
}

// ---------------------------------------------------------------------------
// Kernel B: dense head + MLP. 256 blocks x 512 threads, 4 graphs per block.
// ---------------------------------------------------------------------------
__global__ __launch_bounds__(512, 2)
void mlp_head_kernel(
    const float* __restrict__ egoH,
    const float* __restrict__ Wd1, const float* __restrict__ bd1,
    const float* __restrict__ Wd2, const float* __restrict__ bd2,
    const float* __restrict__ Wf1, const float* __restrict__ bf1,
    const float* __restrict__ Wf2, const float* __restrict__ bf2,
    const float* __restrict__ Wm,  const float* __restrict__ bm,
    const float* __restrict__ Ws,  const float* __restrict__ bs,
    float* __restrict__ out)
{
  __shared__ float hE[4 * C2_];
  __shared__ float t1[4 * NG_];
  __shared__ float dbuf[4 * OBS_];
  __shared__ float f1b[4 * 256];
  __shared__ float f2b[4 * 256];

  const int g0  = blockIdx.x * 4;
  const int tid = threadIdx.x;

  for (int i = tid; i < 4 * C2_; i += 512) hE[i] = egoH[g0 * C2_ + i];
  __syncthreads();

  // t1 = ego @ Wd1^T + bd1   [4][32]
  if (tid < 4 * NG_) {
    const int g = tid >> 5, o = tid & 31;
    float acc = bd1[o];
    const float* w  = &Wd1[o * C2_];
    const float* hp = &hE[g * C2_];
    for (int k = 0; k < C2_; k += 4) {
      float4 hv = *(const float4*)(hp + k);
      float4 wv = *(const float4*)(w + k);
      acc = fmaf(hv.x, wv.x, acc); acc = fmaf(hv.y, wv.y, acc);
      acc = fmaf(hv.z, wv.z, acc); acc = fmaf(hv.w, wv.w, acc);
    }
    t1[tid] = acc;
  }
  __syncthreads();

  // d = tanh(t1 @ Wd2^T + bd2)   [4][512]
  for (int idx = tid; idx < 4 * OBS_; idx += 512) {
    const int g = idx >> 9, o = idx & 511;
    float acc = bd2[o];
    const float* w  = &Wd2[o * NG_];
    const float* tp = &t1[g * NG_];
#pragma unroll
    for (int k = 0; k < NG_; k += 4) {
      float4 tv = *(const float4*)(tp + k);
      float4 wv = *(const float4*)(w + k);
      acc = fmaf(tv.x, wv.x, acc); acc = fmaf(tv.y, wv.y, acc);
      acc = fmaf(tv.z, wv.z, acc); acc = fmaf(tv.w, wv.w, acc);
    }
    dbuf[idx] = tanhf(acc);
  }
  __syncthreads();

  // f1 = relu(d @ Wf1^T + bf1)  [4][256]; thread=(o, graph-pair)
  {
    const int o = tid & 255, gg = tid >> 8;
    const float* w  = &Wf1[o * OBS_];
    const float* dA = &dbuf[(gg * 2 + 0) * OBS_];
    const float* dB = &dbuf[(gg * 2 + 1) * OBS_];
    float a0 = bf1[o], a1 = a0;
#pragma unroll 2
    for (int k = 0; k < OBS_; k += 4) {
      float4 wv = *(const float4*)(w + k);
      float4 xA = *(const float4*)(dA + k);
      float4 xB = *(const float4*)(dB + k);
      a0 = fmaf(xA.x, wv.x, a0); a0 = fmaf(xA.y, wv.y, a0);
      a0 = fmaf(xA.z, wv.z, a0); a0 = fmaf(xA.w, wv.w, a0);
      a1 = fmaf(xB.x, wv.x, a1); a1 = fmaf(xB.y, wv.y, a1);
      a1 = fmaf(xB.z, wv.z, a1); a1 = fmaf(xB.w, wv.w, a1);
    }
    f1b[(gg * 2 + 0) * 256 + o] = fmaxf(a0, 0.f);
    f1b[(gg * 2 + 1) * 256 + o] = fmaxf(a1, 0.f);
  }
  __syncthreads();

  // f2 = relu(f1 @ Wf2^T + bf2)  [4][256]
  {
    const int o = tid & 255, gg = tid >> 8;
    const float* w  = &Wf2[o * 256];
    const float* dA = &f1b[(gg * 2 + 0) * 256];
    const float* dB = &f1b[(gg * 2 + 1) * 256];
    float a0 = bf2[o], a1 = a0;
#pragma unroll 2
    for (int k = 0; k < 256; k += 4) {
      float4 wv = *(const float4*)(w + k);
      float4 xA = *(const float4*)(dA + k);
      float4 xB = *(const float4*)(dB + k);
      a0 = fmaf(xA.x, wv.x, a0); a0 = fmaf(xA.y, wv.y, a0);
      a0 = fmaf(xA.z, wv.z, a0); a0 = fmaf(xA.w, wv.w, a0);
      a1 = fmaf(xB.x, wv.x, a1); a1 = fmaf(xB.y, wv.y, a1);
      a1 = fmaf(xB.z, wv.z, a1); a1 = fmaf(xB.w, wv.w, a1);
    }
    f2b[(gg * 2 + 0) * 256 + o] = fmaxf(a0, 0.f);
    f2b[(gg * 2 + 1) * 256 + o] = fmaxf(a1, 0.f);
  }
  __syncthreads();

  // heads: mean, log_std — 4 graphs x 2 actions x {mean, std}
  if (tid < 16) {
    const int g  = tid >> 2;
    const int a  = (tid >> 1) & 1;
    const int hm = tid & 1;
    const float* fp = &f2b[g * 256];
    const float* w  = hm ? &Ws[a * 256] : &Wm[a * 256];
    float acc = hm ? bs[a] : bm[a];
    for (int k = 0; k < 256; ++k) acc = fmaf(fp[k], w[k], acc);
    if (hm == 0) out[(g0 + g) * 2 + a] = acc;
    else         out[2048 + (g0 + g) * 2 + a] = -5.0f + 3.5f * (tanhf(acc) + 1.0f);
  }
}

extern "C" void kernel_launch(void* const* d_in, const int* in_sizes, int n_in,
                              void* d_out, int out_size, void* d_ws, size_t ws_size,
                              hipStream_t stream) {
  const float* x     = (const float*)d_in[0];
  const int*   eidx  = (const int*)d_in[1];
  const float* eattr = (const float*)d_in[2];
  const float* Wl1 = (const float*)d_in[3];  const float* bl1 = (const float*)d_in[4];
  const float* Wr1 = (const float*)d_in[5];  const float* br1 = (const float*)d_in[6];
  const float* We1 = (const float*)d_in[7];  const float* att1= (const float*)d_in[8];
  const float* bc1 = (const float*)d_in[9];
  const float* Wl2 = (const float*)d_in[10]; const float* bl2 = (const float*)d_in[11];
  const float* Wr2 = (const float*)d_in[12]; const float* br2 = (const float*)d_in[13];
  const float* We2 = (const float*)d_in[14]; const float* att2= (const float*)d_in[15];
  const float* bc2 = (const float*)d_in[16];
  const float* Wd1 = (const float*)d_in[17]; const float* bd1 = (const float*)d_in[18];
  const float* Wd2 = (const float*)d_in[19]; const float* bd2 = (const float*)d_in[20];
  const float* Wf1 = (const float*)d_in[21]; const float* bf1 = (const float*)d_in[22];
  const float* Wf2 = (const float*)d_in[23]; const float* bf2 = (const float*)d_in[24];
  const float* Wm  = (const float*)d_in[25]; const float* bm  = (const float*)d_in[26];
  const float* Ws  = (const float*)d_in[27]; const float* bs  = (const float*)d_in[28];

  float* egoH = (float*)d_ws;   // [1024][160] fp32 = 640 KB

  gnn_two_layer_kernel<<<B_, 512, 0, stream>>>(
      x, eidx, eattr, Wl1, bl1, Wr1, br1, We1, att1, bc1,
      Wl2, bl2, Wr2, br2, We2, att2, bc2, egoH);

  mlp_head_kernel<<<B_ / 4, 512, 0, stream>>>(
      egoH, Wd1, bd1, Wd2, bd2, Wf1, bf1, Wf2, bf2, Wm, bm, Ws, bs,
      (float*)d_out);
}

// Round 4
// 331.140 us; speedup vs baseline: 1.4857x; 1.4857x over previous
//
#include <hip/hip_runtime.h>

#define B_    1024
#define NG_   32
#define F_    16
#define ED_   6
#define EG_   256
#define ET_   262144
#define H1_   5
#define C1_   80
#define HC1_  400
#define C2_   160
#define OBS_  512

#define S1_   408   // bf16 element stride for 400-wide node rows
#define MSG_S 161

typedef unsigned short ushort8v __attribute__((ext_vector_type(8)));

__device__ __forceinline__ float bf2f(unsigned short u) {
  return __uint_as_float(((unsigned int)u) << 16);
}
__device__ __forceinline__ unsigned short f2bf(float f) {
  unsigned int u = __float_as_uint(f);
  u = u + 0x7FFFu + ((u >> 16) & 1u);   // RNE
  return (unsigned short)(u >> 16);
}
__device__ __forceinline__ float dot8(ushort8v hv, float4 wa, float4 wb, float acc) {
  acc = fmaf(bf2f(hv[0]), wa.x, acc);
  acc = fmaf(bf2f(hv[1]), wa.y, acc);
  acc = fmaf(bf2f(hv[2]), wa.z, acc);
  acc = fmaf(bf2f(hv[3]), wa.w, acc);
  acc = fmaf(bf2f(hv[4]), wb.x, acc);
  acc = fmaf(bf2f(hv[5]), wb.y, acc);
  acc = fmaf(bf2f(hv[6]), wb.z, acc);
  acc = fmaf(bf2f(hv[7]), wb.w, acc);
  return acc;
}

// ---------------------------------------------------------------------------
// Kernel A: one block (512 threads) per graph.
// ---------------------------------------------------------------------------
__global__ __launch_bounds__(512, 4)
void gnn_two_layer_kernel(
    const float* __restrict__ x, const int* __restrict__ eidx,
    const float* __restrict__ eattr,
    const float* __restrict__ Wl1, const float* __restrict__ bl1,
    const float* __restrict__ Wr1, const float* __restrict__ br1,
    const float* __restrict__ We1, const float* __restrict__ att1,
    const float* __restrict__ bc1,
    const float* __restrict__ Wl2, const float* __restrict__ bl2,
    const float* __restrict__ Wr2, const float* __restrict__ br2,
    const float* __restrict__ We2, const float* __restrict__ att2,
    const float* __restrict__ bc2,
    float* __restrict__ egoH)
{
  __shared__ __align__(16) unsigned short xl[NG_ * S1_];   // layer-1 msg (bf16); aliased as msgAll in phase 7
  __shared__ __align__(16) unsigned short xrh[NG_ * S1_];  // xr, then h
  __shared__ float sc0[EG_ * H1_];
  __shared__ float sc1[EG_ * H1_];            // aliased as xr2vB in phase 7
  __shared__ float ea[EG_ * ED_];
  __shared__ float xloc[NG_ * F_];
  __shared__ int   esrc[EG_], edst[EG_], eorder[EG_];
  __shared__ int   bstart[NG_ + 1];
  __shared__ float deninv[NG_ * H1_];
  __shared__ float out2[C2_], xr2v[C2_];
  __shared__ float sArr[32], wArr[32];
  __shared__ float mrun_s, denrun_s, scale_s;

  float* const msgAll = (float*)xl;           // 32 x MSG_S fits in xl's 26 KB
  float* const xr2vB  = sc1;

  const int b   = blockIdx.x;
  const int tid = threadIdx.x;
  const int n0  = b * NG_;
  const int eb  = b * EG_;

  // ---------------- phase 1: loads ----------------
  if (tid < EG_) {
    esrc[tid] = eidx[eb + tid] - n0;
    edst[tid] = eidx[ET_ + eb + tid] - n0;
  }
  for (int i = tid; i < EG_ * ED_; i += 512) ea[i] = eattr[eb * ED_ + i];
  if (tid < NG_ * F_) xloc[tid] = x[n0 * F_ + tid];
  __syncthreads();

  // ---------------- phase 2: node transforms (waves 0-6) ||
  // ---------------- phase 4: bucket build (wave 7) ----------------
  if (tid < 448) {
    // c-major: thread owns output channel(s); W row loaded per-lane coalesced.
    for (int t = 0; t < 2; ++t) {
      const int ch = tid + t * 448;
      if (ch >= 800) break;
      const bool isL = (ch < 400);
      const int  c   = isL ? ch : ch - 400;
      const float* Wp = (isL ? Wl1 : Wr1) + c * F_;
      const float bias = isL ? bl1[c] : br1[c];
      unsigned short* dst = (isL ? xl : xrh) + c;
      float w[16];
#pragma unroll
      for (int qk = 0; qk < 4; ++qk) {
        float4 v = *(const float4*)(Wp + qk * 4);
        w[qk*4+0] = v.x; w[qk*4+1] = v.y; w[qk*4+2] = v.z; w[qk*4+3] = v.w;
      }
      for (int n = 0; n < NG_; n += 2) {
        const float* xa = &xloc[n * F_];
        float accA = bias, accB = bias;
#pragma unroll
        for (int qk = 0; qk < 4; ++qk) {
          float4 a = *(const float4*)(xa + qk * 4);
          float4 bv = *(const float4*)(xa + F_ + qk * 4);
          accA = fmaf(a.x,  w[qk*4+0], accA); accA = fmaf(a.y,  w[qk*4+1], accA);
          accA = fmaf(a.z,  w[qk*4+2], accA); accA = fmaf(a.w,  w[qk*4+3], accA);
          accB = fmaf(bv.x, w[qk*4+0], accB); accB = fmaf(bv.y, w[qk*4+1], accB);
          accB = fmaf(bv.z, w[qk*4+2], accB); accB = fmaf(bv.w, w[qk*4+3], accB);
        }
        dst[n * S1_]       = f2bf(accA);
        dst[(n + 1) * S1_] = f2bf(accB);
      }
    }
  } else {
    // wave 7: deterministic counting sort of edges by dst (wave-synchronous)
    const int lane = tid & 63;
    const int d    = lane & 31;
    const int half = lane >> 5;
    int cnt = 0;
    const int4* ed4 = (const int4*)edst;
    for (int i = 0; i < 32; ++i) {
      int4 v = ed4[half * 32 + i];
      cnt += (v.x == d) + (v.y == d) + (v.z == d) + (v.w == d);
    }
    const int cnt_lo = __shfl(cnt, d);            // lo-half count of this d
    const int total  = cnt + __shfl_xor(cnt, 32); // both halves
    int pre = total;                               // inclusive prefix over d
#pragma unroll
    for (int off = 1; off < 32; off <<= 1) {
      int tt = __shfl(pre, lane - off);
      if (d >= off) pre += tt;
    }
    const int start = pre - total;
    if (lane < 32) { bstart[d] = start; if (d == 31) bstart[32] = pre; }
    int p = start + (half ? cnt_lo : 0);
    for (int i = 0; i < 32; ++i) {
      int4 v = ed4[half * 32 + i];
      const int e = half * 128 + i * 4;
      if (v.x == d) eorder[p++] = e;
      if (v.y == d) eorder[p++] = e + 1;
      if (v.z == d) eorder[p++] = e + 2;
      if (v.w == d) eorder[p++] = e + 3;
    }
  }
  __syncthreads();

  // ---------------- phase 3: edge scores (edge x channel-half) ----------------
  {
    const int e = tid & 255;
    const int s = __builtin_amdgcn_readfirstlane((int)(tid >> 8) & 1);  // wave-uniform
    float* const scp = s ? sc1 : sc0;
    const int sl = esrc[e], dl = edst[e];
    const float e0 = ea[e*ED_+0], e1 = ea[e*ED_+1], e2 = ea[e*ED_+2];
    const float e3 = ea[e*ED_+3], e4 = ea[e*ED_+4], e5 = ea[e*ED_+5];
    const unsigned short* xlrow = &xl[sl * S1_ + s * 40];
    const unsigned short* xrrow = &xrh[dl * S1_ + s * 40];
#pragma unroll
    for (int h = 0; h < H1_; ++h) {
      float sh = 0.f;
#pragma unroll
      for (int co = 0; co < 5; ++co) {
        const int coff  = h * C1_ + co * 8;          // offset within (already s-shifted) row
        const int cbase = coff + s * 40;             // uniform channel index for weights
        ushort8v av = *(const ushort8v*)(xlrow + coff);
        ushort8v rv = *(const ushort8v*)(xrrow + coff);
#pragma unroll
        for (int u = 0; u < 8; ++u) {
          const float* wv6 = &We1[(cbase + u) * ED_];
          float t0 = fmaf(wv6[1], e1, wv6[0] * e0);
          float t1 = fmaf(wv6[3], e3, wv6[2] * e2);
          float t2 = fmaf(wv6[5], e5, wv6[4] * e4);
          float p = (bf2f(av[u]) + bf2f(rv[u])) + (t0 + (t1 + t2));
          p = fmaxf(p, 0.2f * p);
          sh = fmaf(p, att1[cbase + u], sh);
        }
      }
      scp[e * H1_ + h] = sh;
    }
  }
  __syncthreads();

  // ---------------- phase 5: segment softmax (store exp & 1/den) --------------
  if (tid < NG_ * H1_) {
    const int d = tid & 31, h = tid >> 5;
    const int s0 = bstart[d], s1 = bstart[d + 1];
    float m = -INFINITY;
    for (int k = s0; k < s1; ++k) {
      const int e5i = eorder[k] * H1_ + h;
      m = fmaxf(m, sc0[e5i] + sc1[e5i]);
    }
    float den = 0.f;
    for (int k = s0; k < s1; ++k) {
      const int e5i = eorder[k] * H1_ + h;
      float t = expf(sc0[e5i] + sc1[e5i] - m);
      den += t;
      sc0[e5i] = t;
    }
    deninv[tid] = 1.f / (den + 1e-16f);   // tid = h*32 + d
  }
  __syncthreads();

  // ---------------- phase 6: aggregation, h = relu((sum ex*msg)*inv + bc1) ----
  for (int idx = tid; idx < NG_ * 50; idx += 512) {
    const int d  = idx / 50;
    const int co = idx - d * 50;
    const int c  = co * 8;
    const int h  = co / 10;
    const int s0 = bstart[d], s1 = bstart[d + 1];
    float acc[8] = {0.f,0.f,0.f,0.f,0.f,0.f,0.f,0.f};
    for (int k = s0; k < s1; ++k) {
      const int e = eorder[k];
      const float al = sc0[e * H1_ + h];
      ushort8v xv = *(const ushort8v*)(&xl[esrc[e] * S1_ + c]);
#pragma unroll
      for (int u = 0; u < 8; ++u) acc[u] = fmaf(al, bf2f(xv[u]), acc[u]);
    }
    const float inv = deninv[h * 32 + d];
    ushort8v hv;
#pragma unroll
    for (int u = 0; u < 8; ++u)
      hv[u] = f2bf(fmaxf(fmaf(acc[u], inv, bc1[c + u]), 0.f));
    *(ushort8v*)(&xrh[d * S1_ + c]) = hv;
  }
  __syncthreads();
  // xl is now dead -> msgAll aliases it; sc1 dead -> xr2vB aliases it.

  // ---------------- phase 7: layer-2, ego node only ----------------
  const int nE = bstart[1];
  const int cc = (tid < 320) ? (tid % 160) : 0;
  const int q  = (tid < 320) ? (tid / 160) : 0;

  // 7a: xr2v = Wr2 @ h[ego] + br2, k-split over q in {0,1}
  float myXr = 0.f;
  if (tid < 320) {
    const float* wr = &Wr2[cc * HC1_ + q * 200];
    const unsigned short* hr = &xrh[q * 200];
    float a0 = 0.f, a1 = 0.f;
#pragma unroll 5
    for (int kk = 0; kk < 25; ++kk) {
      const int k = kk * 8;
      ushort8v hv = *(const ushort8v*)(hr + k);
      float4 wa = *(const float4*)(wr + k);
      float4 wb = *(const float4*)(wr + k + 4);
      if (kk & 1) a1 = dot8(hv, wa, wb, a1); else a0 = dot8(hv, wa, wb, a0);
    }
    const float a = a0 + a1;
    if (q == 1) xr2vB[cc] = a; else myXr = a;
  }
  if (tid < C2_) out2[tid] = 0.f;
  if (tid == 0) { mrun_s = -INFINITY; denrun_s = 0.f; scale_s = 0.f; }
  __syncthreads();
  if (tid < C2_) xr2v[tid] = myXr + xr2vB[tid] + br2[tid];   // q==0 threads == tid<160

  // 7b: groups of up to 32 ego-edges
  for (int g0 = 0; g0 < nE; g0 += 32) {
    const int ng = min(32, nE - g0);

    // (i) messages: thread=(cc, j-parity q); Wl2 row read once per thread
    for (int jb = 0; jb < ng; jb += 8) {
      const int jn = min(8, ng - jb);
      if (tid < 320) {
        const int nj = (jn + 1 - q) >> 1;    // q=0: ceil(jn/2), q=1: floor
        const float* wl = &Wl2[cc * HC1_];
        const float blv = bl2[cc];
        if (nj == 4) {
          const int r0 = esrc[eorder[g0 + jb + q + 0]] * S1_;
          const int r1 = esrc[eorder[g0 + jb + q + 2]] * S1_;
          const int r2 = esrc[eorder[g0 + jb + q + 4]] * S1_;
          const int r3 = esrc[eorder[g0 + jb + q + 6]] * S1_;
          float a0 = 0.f, a1 = 0.f, a2 = 0.f, a3 = 0.f;
#pragma unroll 2
          for (int kk = 0; kk < 50; ++kk) {
            const int k = kk * 8;
            float4 wa = *(const float4*)(wl + k);
            float4 wb = *(const float4*)(wl + k + 4);
            a0 = dot8(*(const ushort8v*)(&xrh[r0 + k]), wa, wb, a0);
            a1 = dot8(*(const ushort8v*)(&xrh[r1 + k]), wa, wb, a1);
            a2 = dot8(*(const ushort8v*)(&xrh[r2 + k]), wa, wb, a2);
            a3 = dot8(*(const ushort8v*)(&xrh[r3 + k]), wa, wb, a3);
          }
          msgAll[(jb + q + 0) * MSG_S + cc] = a0 + blv;
          msgAll[(jb + q + 2) * MSG_S + cc] = a1 + blv;
          msgAll[(jb + q + 4) * MSG_S + cc] = a2 + blv;
          msgAll[(jb + q + 6) * MSG_S + cc] = a3 + blv;
        } else {
          for (int i = 0; i < nj; ++i) {       // rare tail: one edge at a time
            const int j = jb + q + 2 * i;
            const int r = esrc[eorder[g0 + j]] * S1_;
            float a0 = 0.f, a1 = 0.f;
#pragma unroll 2
            for (int kk = 0; kk < 50; ++kk) {
              const int k = kk * 8;
              float4 wa = *(const float4*)(wl + k);
              float4 wb = *(const float4*)(wl + k + 4);
              if (kk & 1) a1 = dot8(*(const ushort8v*)(&xrh[r + k]), wa, wb, a1);
              else        a0 = dot8(*(const ushort8v*)(&xrh[r + k]), wa, wb, a0);
            }
            msgAll[j * MSG_S + cc] = a0 + a1 + blv;
          }
        }
      }
      __syncthreads();
    }

    // (ii) scores: 8 lanes per edge, shfl reduce
    if (tid < 256) {
      const int j  = tid >> 3;
      const int q8 = tid & 7;
      float s = 0.f;
      if (j < ng) {
        const int e = eorder[g0 + j];
        const float e0 = ea[e*ED_+0], e1 = ea[e*ED_+1], e2 = ea[e*ED_+2];
        const float e3 = ea[e*ED_+3], e4 = ea[e*ED_+4], e5 = ea[e*ED_+5];
        const float* mrow = &msgAll[j * MSG_S];
        for (int i = 0; i < 20; ++i) {
          const int c2 = q8 * 20 + i;
          const float* wv6 = &We2[c2 * ED_];
          float t0 = fmaf(wv6[1], e1, wv6[0] * e0);
          float t1 = fmaf(wv6[3], e3, wv6[2] * e2);
          float t2 = fmaf(wv6[5], e5, wv6[4] * e4);
          float p = mrow[c2] + xr2v[c2] + (t0 + (t1 + t2));
          p = fmaxf(p, 0.2f * p);
          s = fmaf(p, att2[c2], s);
        }
      }
      s += __shfl_xor(s, 1); s += __shfl_xor(s, 2); s += __shfl_xor(s, 4);
      if (q8 == 0 && j < ng) sArr[j] = s;
    }
    __syncthreads();

    // (iii) wave-parallel softmax + online merge (wave 0)
    if (tid < 64) {
      const int j = tid & 31;
      float s = (j < ng) ? sArr[j] : -INFINITY;
      float mg = s;
      mg = fmaxf(mg, __shfl_xor(mg, 1));
      mg = fmaxf(mg, __shfl_xor(mg, 2));
      mg = fmaxf(mg, __shfl_xor(mg, 4));
      mg = fmaxf(mg, __shfl_xor(mg, 8));
      mg = fmaxf(mg, __shfl_xor(mg, 16));
      const float mold = mrun_s;
      const float mnew = fmaxf(mold, mg);
      float w = (j < ng) ? expf(s - mnew) : 0.f;
      float dg = w;
      dg += __shfl_xor(dg, 1); dg += __shfl_xor(dg, 2); dg += __shfl_xor(dg, 4);
      dg += __shfl_xor(dg, 8); dg += __shfl_xor(dg, 16);
      if (tid < 32 && j < ng) wArr[j] = w;
      if (tid == 0) {
        const float scl = expf(mold - mnew);   // 0 on first group
        scale_s  = scl;
        denrun_s = denrun_s * scl + dg;
        mrun_s   = mnew;
      }
    }
    __syncthreads();

    // (iv) accumulate
    if (tid < C2_) {
      float o = out2[tid] * scale_s;
      for (int j = 0; j < ng; ++j) o = fmaf(wArr[j], msgAll[j * MSG_S + tid], o);
      out2[tid] = o;
    }
    __syncthreads();
  }

  if (tid < C2_) {
    const float v = out2[tid] / (denrun_s + 1e-16f) + bc2[tid];
    egoH[b * C2_ + tid] = fmaxf(v, 0.f);
  }
}

// ---------------------------------------------------------------------------
// Kernel B: dense head + MLP. 256 blocks x 512 threads, 4 graphs per block.
// ---------------------------------------------------------------------------
__global__ __launch_bounds__(512, 2)
void mlp_head_kernel(
    const float* __restrict__ egoH,
    const float* __restrict__ Wd1, const float* __restrict__ bd1,
    const float* __restrict__ Wd2, const float* __restrict__ bd2,
    const float* __restrict__ Wf1, const float* __restrict__ bf1,
    const float* __restrict__ Wf2, const float* __restrict__ bf2,
    const float* __restrict__ Wm,  const float* __restrict__ bm,
    const float* __restrict__ Ws,  const float* __restrict__ bs,
    float* __restrict__ out)
{
  __shared__ float hE[4 * C2_];
  __shared__ float t1[4 * NG_];
  __shared__ float dbuf[4 * OBS_];
  __shared__ float f1b[4 * 256];
  __shared__ float f2b[4 * 256];

  const int g0  = blockIdx.x * 4;
  const int tid = threadIdx.x;

  for (int i = tid; i < 4 * C2_; i += 512) hE[i] = egoH[g0 * C2_ + i];
  __syncthreads();

  if (tid < 4 * NG_) {
    const int g = tid >> 5, o = tid & 31;
    float acc = bd1[o];
    const float* w  = &Wd1[o * C2_];
    const float* hp = &hE[g * C2_];
    for (int k = 0; k < C2_; k += 4) {
      float4 hv = *(const float4*)(hp + k);
      float4 wv = *(const float4*)(w + k);
      acc = fmaf(hv.x, wv.x, acc); acc = fmaf(hv.y, wv.y, acc);
      acc = fmaf(hv.z, wv.z, acc); acc = fmaf(hv.w, wv.w, acc);
    }
    t1[tid] = acc;
  }
  __syncthreads();

  for (int idx = tid; idx < 4 * OBS_; idx += 512) {
    const int g = idx >> 9, o = idx & 511;
    float acc = bd2[o];
    const float* w  = &Wd2[o * NG_];
    const float* tp = &t1[g * NG_];
#pragma unroll
    for (int k = 0; k < NG_; k += 4) {
      float4 tv = *(const float4*)(tp + k);
      float4 wv = *(const float4*)(w + k);
      acc = fmaf(tv.x, wv.x, acc); acc = fmaf(tv.y, wv.y, acc);
      acc = fmaf(tv.z, wv.z, acc); acc = fmaf(tv.w, wv.w, acc);
    }
    dbuf[idx] = tanhf(acc);
  }
  __syncthreads();

  {
    const int o = tid & 255, gg = tid >> 8;
    const float* w  = &Wf1[o * OBS_];
    const float* dA = &dbuf[(gg * 2 + 0) * OBS_];
    const float* dB = &dbuf[(gg * 2 + 1) * OBS_];
    float a0 = bf1[o], a1 = a0;
#pragma unroll 2
    for (int k = 0; k < OBS_; k += 4) {
      float4 wv = *(const float4*)(w + k);
      float4 xA = *(const float4*)(dA + k);
      float4 xB = *(const float4*)(dB + k);
      a0 = fmaf(xA.x, wv.x, a0); a0 = fmaf(xA.y, wv.y, a0);
      a0 = fmaf(xA.z, wv.z, a0); a0 = fmaf(xA.w, wv.w, a0);
      a1 = fmaf(xB.x, wv.x, a1); a1 = fmaf(xB.y, wv.y, a1);
      a1 = fmaf(xB.z, wv.z, a1); a1 = fmaf(xB.w, wv.w, a1);
    }
    f1b[(gg * 2 + 0) * 256 + o] = fmaxf(a0, 0.f);
    f1b[(gg * 2 + 1) * 256 + o] = fmaxf(a1, 0.f);
  }
  __syncthreads();

  {
    const int o = tid & 255, gg = tid >> 8;
    const float* w  = &Wf2[o * 256];
    const float* dA = &f1b[(gg * 2 + 0) * 256];
    const float* dB = &f1b[(gg * 2 + 1) * 256];
    float a0 = bf2[o], a1 = a0;
#pragma unroll 2
    for (int k = 0; k < 256; k += 4) {
      float4 wv = *(const float4*)(w + k);
      float4 xA = *(const float4*)(dA + k);
      float4 xB = *(const float4*)(dB + k);
      a0 = fmaf(xA.x, wv.x, a0); a0 = fmaf(xA.y, wv.y, a0);
      a0 = fmaf(xA.z, wv.z, a0); a0 = fmaf(xA.w, wv.w, a0);
      a1 = fmaf(xB.x, wv.x, a1); a1 = fmaf(xB.y, wv.y, a1);
      a1 = fmaf(xB.z, wv.z, a1); a1 = fmaf(xB.w, wv.w, a1);
    }
    f2b[(gg * 2 + 0) * 256 + o] = fmaxf(a0, 0.f);
    f2b[(gg * 2 + 1) * 256 + o] = fmaxf(a1, 0.f);
  }
  __syncthreads();

  if (tid < 16) {
    const int g  = tid >> 2;
    const int a  = (tid >> 1) & 1;
    const int hm = tid & 1;
    const float* fp = &f2b[g * 256];
    const float* w  = hm ? &Ws[a * 256] : &Wm[a * 256];
    float acc = hm ? bs[a] : bm[a];
    for (int k = 0; k < 256; ++k) acc = fmaf(fp[k], w[k], acc);
    if (hm == 0) out[(g0 + g) * 2 + a] = acc;
    else         out[2048 + (g0 + g) * 2 + a] = -5.0f + 3.5f * (tanhf(acc) + 1.0f);
  }
}

extern "C" void kernel_launch(void* const* d_in, const int* in_sizes, int n_in,
                              void* d_out, int out_size, void* d_ws, size_t ws_size,
                              hipStream_t stream) {
  const float* x     = (const float*)d_in[0];
  const int*   eidx  = (const int*)d_in[1];
  const float* eattr = (const float*)d_in[2];
  const float* Wl1 = (const float*)d_in[3];  const float* bl1 = (const float*)d_in[4];
  const float* Wr1 = (const float*)d_in[5];  const float* br1 = (const float*)d_in[6];
  const float* We1 = (const float*)d_in[7];  const float* att1= (const float*)d_in[8];
  const float* bc1 = (const float*)d_in[9];
  const float* Wl2 = (const float*)d_in[10]; const float* bl2 = (const float*)d_in[11];
  const float* Wr2 = (const float*)d_in[12]; const float* br2 = (const float*)d_in[13];
  const float* We2 = (const float*)d_in[14]; const float* att2= (const float*)d_in[15];
  const float* bc2 = (const float*)d_in[16];
  const float* Wd1 = (const float*)d_in[17]; const float* bd1 = (const float*)d_in[18];
  const float* Wd2 = (const float*)d_in[19]; const float* bd2 = (const float*)d_in[20];
  const float* Wf1 = (const float*)d_in[21]; const float* bf1 = (const float*)d_in[22];
  const float* Wf2 = (const float*)d_in[23]; const float* bf2 = (const float*)d_in[24];
  const float* Wm  = (const float*)d_in[25]; const float* bm  = (const float*)d_in[26];
  const float* Ws  = (const float*)d_in[27]; const float* bs  = (const float*)d_in[28];

  float* egoH = (float*)d_ws;   // [1024][160] fp32 = 640 KB

  gnn_two_layer_kernel<<<B_, 512, 0, stream>>>(
      x, eidx, eattr, Wl1, bl1, Wr1, br1, We1, att1, bc1,
      Wl2, bl2, Wr2, br2, We2, att2, bc2, egoH);

  mlp_head_kernel<<<B_ / 4, 512, 0, stream>>>(
      egoH, Wd1, bd1, Wd2, bd2, Wf1, bf1, Wf2, bf2, Wm, bm, Ws, bs,
      (float*)d_out);
}

// Round 5
// 307.675 us; speedup vs baseline: 1.5990x; 1.0763x over previous
//
#include <hip/hip_runtime.h>

#define B_    1024
#define NG_   32
#define F_    16
#define ED_   6
#define EG_   256
#define ET_   262144
#define H1_   5
#define C1_   80
#define HC1_  400
#define C2_   160
#define OBS_  512

#define S1_   408   // bf16 element stride for 400-wide node rows
#define MSG_S 161

typedef unsigned short ushort8v __attribute__((ext_vector_type(8)));

__device__ __forceinline__ float bf2f(unsigned short u) {
  return __uint_as_float(((unsigned int)u) << 16);
}
__device__ __forceinline__ unsigned short f2bf(float f) {
  unsigned int u = __float_as_uint(f);
  u = u + 0x7FFFu + ((u >> 16) & 1u);   // RNE
  return (unsigned short)(u >> 16);
}
__device__ __forceinline__ float dot8(ushort8v hv, float4 wa, float4 wb, float acc) {
  acc = fmaf(bf2f(hv[0]), wa.x, acc);
  acc = fmaf(bf2f(hv[1]), wa.y, acc);
  acc = fmaf(bf2f(hv[2]), wa.z, acc);
  acc = fmaf(bf2f(hv[3]), wa.w, acc);
  acc = fmaf(bf2f(hv[4]), wb.x, acc);
  acc = fmaf(bf2f(hv[5]), wb.y, acc);
  acc = fmaf(bf2f(hv[6]), wb.z, acc);
  acc = fmaf(bf2f(hv[7]), wb.w, acc);
  return acc;
}

// ---------------------------------------------------------------------------
// Kernel A: one block (512 threads) per graph. LDS caps occupancy at
// 2 blocks/CU, so min-waves=2; (512,4) forced 64-VGPR spills (r4: 213 MB
// scratch writes) — do not raise.
// ---------------------------------------------------------------------------
__global__ __launch_bounds__(512, 2)
void gnn_two_layer_kernel(
    const float* __restrict__ x, const int* __restrict__ eidx,
    const float* __restrict__ eattr,
    const float* __restrict__ Wl1, const float* __restrict__ bl1,
    const float* __restrict__ Wr1, const float* __restrict__ br1,
    const float* __restrict__ We1, const float* __restrict__ att1,
    const float* __restrict__ bc1,
    const float* __restrict__ Wl2, const float* __restrict__ bl2,
    const float* __restrict__ Wr2, const float* __restrict__ br2,
    const float* __restrict__ We2, const float* __restrict__ att2,
    const float* __restrict__ bc2,
    float* __restrict__ egoH)
{
  __shared__ __align__(16) unsigned short xl[NG_ * S1_];   // layer-1 msg (bf16); aliased as msgAll in phase 7
  __shared__ __align__(16) unsigned short xrh[NG_ * S1_];  // xr, then h
  __shared__ float sc0[EG_ * H1_];
  __shared__ float sc1[EG_ * H1_];            // aliased as xr2vB in phase 7
  __shared__ float ea[EG_ * ED_];
  __shared__ float xloc[NG_ * F_];
  __shared__ int   esrc[EG_], edst[EG_], eorder[EG_];
  __shared__ int   bstart[NG_ + 1];
  __shared__ float deninv[NG_ * H1_];
  __shared__ float out2[C2_], xr2v[C2_];
  __shared__ float sArr[32], wArr[32];
  __shared__ float mrun_s, denrun_s, scale_s;

  float* const msgAll = (float*)xl;           // 32 x MSG_S fits in xl's 26 KB
  float* const xr2vB  = sc1;

  const int b   = blockIdx.x;
  const int tid = threadIdx.x;
  const int n0  = b * NG_;
  const int eb  = b * EG_;

  // ---------------- phase 1: loads ----------------
  if (tid < EG_) {
    esrc[tid] = eidx[eb + tid] - n0;
    edst[tid] = eidx[ET_ + eb + tid] - n0;
  }
  for (int i = tid; i < EG_ * ED_; i += 512) ea[i] = eattr[eb * ED_ + i];
  if (tid < NG_ * F_) xloc[tid] = x[n0 * F_ + tid];
  __syncthreads();

  // ---------------- phase 2: node transforms (waves 0-6) ||
  // ---------------- phase 4: bucket build (wave 7) ----------------
  if (tid < 448) {
    // c-major: thread owns output channel(s); W row loaded per-lane coalesced.
    for (int t = 0; t < 2; ++t) {
      const int ch = tid + t * 448;
      if (ch >= 800) break;
      const bool isL = (ch < 400);
      const int  c   = isL ? ch : ch - 400;
      const float* Wp = (isL ? Wl1 : Wr1) + c * F_;
      const float bias = isL ? bl1[c] : br1[c];
      unsigned short* dst = (isL ? xl : xrh) + c;
      float w[16];
#pragma unroll
      for (int qk = 0; qk < 4; ++qk) {
        float4 v = *(const float4*)(Wp + qk * 4);
        w[qk*4+0] = v.x; w[qk*4+1] = v.y; w[qk*4+2] = v.z; w[qk*4+3] = v.w;
      }
      for (int n = 0; n < NG_; n += 2) {
        const float* xa = &xloc[n * F_];
        float accA = bias, accB = bias;
#pragma unroll
        for (int qk = 0; qk < 4; ++qk) {
          float4 a = *(const float4*)(xa + qk * 4);
          float4 bv = *(const float4*)(xa + F_ + qk * 4);
          accA = fmaf(a.x,  w[qk*4+0], accA); accA = fmaf(a.y,  w[qk*4+1], accA);
          accA = fmaf(a.z,  w[qk*4+2], accA); accA = fmaf(a.w,  w[qk*4+3], accA);
          accB = fmaf(bv.x, w[qk*4+0], accB); accB = fmaf(bv.y, w[qk*4+1], accB);
          accB = fmaf(bv.z, w[qk*4+2], accB); accB = fmaf(bv.w, w[qk*4+3], accB);
        }
        dst[n * S1_]       = f2bf(accA);
        dst[(n + 1) * S1_] = f2bf(accB);
      }
    }
  } else {
    // wave 7: deterministic counting sort of edges by dst (wave-synchronous)
    const int lane = tid & 63;
    const int d    = lane & 31;
    const int half = lane >> 5;
    int cnt = 0;
    const int4* ed4 = (const int4*)edst;
    for (int i = 0; i < 32; ++i) {
      int4 v = ed4[half * 32 + i];
      cnt += (v.x == d) + (v.y == d) + (v.z == d) + (v.w == d);
    }
    const int cnt_lo = __shfl(cnt, d);            // lo-half count of this d
    const int total  = cnt + __shfl_xor(cnt, 32); // both halves
    int pre = total;                               // inclusive prefix over d
#pragma unroll
    for (int off = 1; off < 32; off <<= 1) {
      int tt = __shfl(pre, lane - off);
      if (d >= off) pre += tt;
    }
    const int start = pre - total;
    if (lane < 32) { bstart[d] = start; if (d == 31) bstart[32] = pre; }
    int p = start + (half ? cnt_lo : 0);
    for (int i = 0; i < 32; ++i) {
      int4 v = ed4[half * 32 + i];
      const int e = half * 128 + i * 4;
      if (v.x == d) eorder[p++] = e;
      if (v.y == d) eorder[p++] = e + 1;
      if (v.z == d) eorder[p++] = e + 2;
      if (v.w == d) eorder[p++] = e + 3;
    }
  }
  __syncthreads();

  // ---------------- phase 3: edge scores (edge x channel-half) ----------------
  {
    const int e = tid & 255;
    const int s = __builtin_amdgcn_readfirstlane((int)(tid >> 8) & 1);  // wave-uniform
    float* const scp = s ? sc1 : sc0;
    const int sl = esrc[e], dl = edst[e];
    const float e0 = ea[e*ED_+0], e1 = ea[e*ED_+1], e2 = ea[e*ED_+2];
    const float e3 = ea[e*ED_+3], e4 = ea[e*ED_+4], e5 = ea[e*ED_+5];
    const unsigned short* xlrow = &xl[sl * S1_ + s * 40];
    const unsigned short* xrrow = &xrh[dl * S1_ + s * 40];
#pragma unroll
    for (int h = 0; h < H1_; ++h) {
      float sh = 0.f;
#pragma unroll
      for (int co = 0; co < 5; ++co) {
        const int coff  = h * C1_ + co * 8;          // offset within (already s-shifted) row
        const int cbase = coff + s * 40;             // uniform channel index for weights
        ushort8v av = *(const ushort8v*)(xlrow + coff);
        ushort8v rv = *(const ushort8v*)(xrrow + coff);
#pragma unroll
        for (int u = 0; u < 8; ++u) {
          const float* wv6 = &We1[(cbase + u) * ED_];
          float t0 = fmaf(wv6[1], e1, wv6[0] * e0);
          float t1 = fmaf(wv6[3], e3, wv6[2] * e2);
          float t2 = fmaf(wv6[5], e5, wv6[4] * e4);
          float p = (bf2f(av[u]) + bf2f(rv[u])) + (t0 + (t1 + t2));
          p = fmaxf(p, 0.2f * p);
          sh = fmaf(p, att1[cbase + u], sh);
        }
      }
      scp[e * H1_ + h] = sh;
    }
  }
  __syncthreads();

  // ---------------- phase 5: segment softmax (store exp & 1/den) --------------
  if (tid < NG_ * H1_) {
    const int d = tid & 31, h = tid >> 5;
    const int s0 = bstart[d], s1 = bstart[d + 1];
    float m = -INFINITY;
    for (int k = s0; k < s1; ++k) {
      const int e5i = eorder[k] * H1_ + h;
      m = fmaxf(m, sc0[e5i] + sc1[e5i]);
    }
    float den = 0.f;
    for (int k = s0; k < s1; ++k) {
      const int e5i = eorder[k] * H1_ + h;
      float t = expf(sc0[e5i] + sc1[e5i] - m);
      den += t;
      sc0[e5i] = t;
    }
    deninv[tid] = 1.f / (den + 1e-16f);   // tid = h*32 + d
  }
  __syncthreads();

  // ---------------- phase 6: aggregation, h = relu((sum ex*msg)*inv + bc1) ----
  for (int idx = tid; idx < NG_ * 50; idx += 512) {
    const int d  = idx / 50;
    const int co = idx - d * 50;
    const int c  = co * 8;
    const int h  = co / 10;
    const int s0 = bstart[d], s1 = bstart[d + 1];
    float acc[8] = {0.f,0.f,0.f,0.f,0.f,0.f,0.f,0.f};
    for (int k = s0; k < s1; ++k) {
      const int e = eorder[k];
      const float al = sc0[e * H1_ + h];
      ushort8v xv = *(const ushort8v*)(&xl[esrc[e] * S1_ + c]);
#pragma unroll
      for (int u = 0; u < 8; ++u) acc[u] = fmaf(al, bf2f(xv[u]), acc[u]);
    }
    const float inv = deninv[h * 32 + d];
    ushort8v hv;
#pragma unroll
    for (int u = 0; u < 8; ++u)
      hv[u] = f2bf(fmaxf(fmaf(acc[u], inv, bc1[c + u]), 0.f));
    *(ushort8v*)(&xrh[d * S1_ + c]) = hv;
  }
  __syncthreads();
  // xl is now dead -> msgAll aliases it; sc1 dead -> xr2vB aliases it.

  // ---------------- phase 7: layer-2, ego node only ----------------
  const int nE = bstart[1];
  const int cc = (tid < 320) ? (tid % 160) : 0;
  const int q  = (tid < 320) ? (tid / 160) : 0;

  // 7a: xr2v = Wr2 @ h[ego] + br2, k-split over q in {0,1}
  float myXr = 0.f;
  if (tid < 320) {
    const float* wr = &Wr2[cc * HC1_ + q * 200];
    const unsigned short* hr = &xrh[q * 200];
    float a0 = 0.f, a1 = 0.f;
#pragma unroll 5
    for (int kk = 0; kk < 25; ++kk) {
      const int k = kk * 8;
      ushort8v hv = *(const ushort8v*)(hr + k);
      float4 wa = *(const float4*)(wr + k);
      float4 wb = *(const float4*)(wr + k + 4);
      if (kk & 1) a1 = dot8(hv, wa, wb, a1); else a0 = dot8(hv, wa, wb, a0);
    }
    const float a = a0 + a1;
    if (q == 1) xr2vB[cc] = a; else myXr = a;
  }
  if (tid < C2_) out2[tid] = 0.f;
  if (tid == 0) { mrun_s = -INFINITY; denrun_s = 0.f; scale_s = 0.f; }
  __syncthreads();
  if (tid < C2_) xr2v[tid] = myXr + xr2vB[tid] + br2[tid];   // q==0 threads == tid<160

  // 7b: groups of up to 32 ego-edges
  for (int g0 = 0; g0 < nE; g0 += 32) {
    const int ng = min(32, nE - g0);

    // (i) messages: thread=(cc, j-parity q); Wl2 row read once per thread
    for (int jb = 0; jb < ng; jb += 8) {
      const int jn = min(8, ng - jb);
      if (tid < 320) {
        const int nj = (jn + 1 - q) >> 1;    // q=0: ceil(jn/2), q=1: floor
        const float* wl = &Wl2[cc * HC1_];
        const float blv = bl2[cc];
        if (nj == 4) {
          const int r0 = esrc[eorder[g0 + jb + q + 0]] * S1_;
          const int r1 = esrc[eorder[g0 + jb + q + 2]] * S1_;
          const int r2 = esrc[eorder[g0 + jb + q + 4]] * S1_;
          const int r3 = esrc[eorder[g0 + jb + q + 6]] * S1_;
          float a0 = 0.f, a1 = 0.f, a2 = 0.f, a3 = 0.f;
#pragma unroll 2
          for (int kk = 0; kk < 50; ++kk) {
            const int k = kk * 8;
            float4 wa = *(const float4*)(wl + k);
            float4 wb = *(const float4*)(wl + k + 4);
            a0 = dot8(*(const ushort8v*)(&xrh[r0 + k]), wa, wb, a0);
            a1 = dot8(*(const ushort8v*)(&xrh[r1 + k]), wa, wb, a1);
            a2 = dot8(*(const ushort8v*)(&xrh[r2 + k]), wa, wb, a2);
            a3 = dot8(*(const ushort8v*)(&xrh[r3 + k]), wa, wb, a3);
          }
          msgAll[(jb + q + 0) * MSG_S + cc] = a0 + blv;
          msgAll[(jb + q + 2) * MSG_S + cc] = a1 + blv;
          msgAll[(jb + q + 4) * MSG_S + cc] = a2 + blv;
          msgAll[(jb + q + 6) * MSG_S + cc] = a3 + blv;
        } else {
          for (int i = 0; i < nj; ++i) {       // rare tail: one edge at a time
            const int j = jb + q + 2 * i;
            const int r = esrc[eorder[g0 + j]] * S1_;
            float a0 = 0.f, a1 = 0.f;
#pragma unroll 2
            for (int kk = 0; kk < 50; ++kk) {
              const int k = kk * 8;
              float4 wa = *(const float4*)(wl + k);
              float4 wb = *(const float4*)(wl + k + 4);
              if (kk & 1) a1 = dot8(*(const ushort8v*)(&xrh[r + k]), wa, wb, a1);
              else        a0 = dot8(*(const ushort8v*)(&xrh[r + k]), wa, wb, a0);
            }
            msgAll[j * MSG_S + cc] = a0 + a1 + blv;
          }
        }
      }
      __syncthreads();
    }

    // (ii) scores: 8 lanes per edge, shfl reduce
    if (tid < 256) {
      const int j  = tid >> 3;
      const int q8 = tid & 7;
      float s = 0.f;
      if (j < ng) {
        const int e = eorder[g0 + j];
        const float e0 = ea[e*ED_+0], e1 = ea[e*ED_+1], e2 = ea[e*ED_+2];
        const float e3 = ea[e*ED_+3], e4 = ea[e*ED_+4], e5 = ea[e*ED_+5];
        const float* mrow = &msgAll[j * MSG_S];
        for (int i = 0; i < 20; ++i) {
          const int c2 = q8 * 20 + i;
          const float* wv6 = &We2[c2 * ED_];
          float t0 = fmaf(wv6[1], e1, wv6[0] * e0);
          float t1 = fmaf(wv6[3], e3, wv6[2] * e2);
          float t2 = fmaf(wv6[5], e5, wv6[4] * e4);
          float p = mrow[c2] + xr2v[c2] + (t0 + (t1 + t2));
          p = fmaxf(p, 0.2f * p);
          s = fmaf(p, att2[c2], s);
        }
      }
      s += __shfl_xor(s, 1); s += __shfl_xor(s, 2); s += __shfl_xor(s, 4);
      if (q8 == 0 && j < ng) sArr[j] = s;
    }
    __syncthreads();

    // (iii) wave-parallel softmax + online merge (wave 0)
    if (tid < 64) {
      const int j = tid & 31;
      float s = (j < ng) ? sArr[j] : -INFINITY;
      float mg = s;
      mg = fmaxf(mg, __shfl_xor(mg, 1));
      mg = fmaxf(mg, __shfl_xor(mg, 2));
      mg = fmaxf(mg, __shfl_xor(mg, 4));
      mg = fmaxf(mg, __shfl_xor(mg, 8));
      mg = fmaxf(mg, __shfl_xor(mg, 16));
      const float mold = mrun_s;
      const float mnew = fmaxf(mold, mg);
      float w = (j < ng) ? expf(s - mnew) : 0.f;
      float dg = w;
      dg += __shfl_xor(dg, 1); dg += __shfl_xor(dg, 2); dg += __shfl_xor(dg, 4);
      dg += __shfl_xor(dg, 8); dg += __shfl_xor(dg, 16);
      if (tid < 32 && j < ng) wArr[j] = w;
      if (tid == 0) {
        const float scl = expf(mold - mnew);   // 0 on first group
        scale_s  = scl;
        denrun_s = denrun_s * scl + dg;
        mrun_s   = mnew;
      }
    }
    __syncthreads();

    // (iv) accumulate
    if (tid < C2_) {
      float o = out2[tid] * scale_s;
      for (int j = 0; j < ng; ++j) o = fmaf(wArr[j], msgAll[j * MSG_S + tid], o);
      out2[tid] = o;
    }
    __syncthreads();
  }

  if (tid < C2_) {
    const float v = out2[tid] / (denrun_s + 1e-16f) + bc2[tid];
    egoH[b * C2_ + tid] = fmaxf(v, 0.f);
  }
}

// ---------------------------------------------------------------------------
// Kernel B: dense head + MLP. 256 blocks x 512 threads, 4 graphs per block.
// ---------------------------------------------------------------------------
__global__ __launch_bounds__(512, 2)
void mlp_head_kernel(
    const float* __restrict__ egoH,
    const float* __restrict__ Wd1, const float* __restrict__ bd1,
    const float* __restrict__ Wd2, const float* __restrict__ bd2,
    const float* __restrict__ Wf1, const float* __restrict__ bf1,
    const float* __restrict__ Wf2, const float* __restrict__ bf2,
    const float* __restrict__ Wm,  const float* __restrict__ bm,
    const float* __restrict__ Ws,  const float* __restrict__ bs,
    float* __restrict__ out)
{
  __shared__ float hE[4 * C2_];
  __shared__ float t1[4 * NG_];
  __shared__ float dbuf[4 * OBS_];
  __shared__ float f1b[4 * 256];
  __shared__ float f2b[4 * 256];

  const int g0  = blockIdx.x * 4;
  const int tid = threadIdx.x;

  for (int i = tid; i < 4 * C2_; i += 512) hE[i] = egoH[g0 * C2_ + i];
  __syncthreads();

  if (tid < 4 * NG_) {
    const int g = tid >> 5, o = tid & 31;
    float acc = bd1[o];
    const float* w  = &Wd1[o * C2_];
    const float* hp = &hE[g * C2_];
    for (int k = 0; k < C2_; k += 4) {
      float4 hv = *(const float4*)(hp + k);
      float4 wv = *(const float4*)(w + k);
      acc = fmaf(hv.x, wv.x, acc); acc = fmaf(hv.y, wv.y, acc);
      acc = fmaf(hv.z, wv.z, acc); acc = fmaf(hv.w, wv.w, acc);
    }
    t1[tid] = acc;
  }
  __syncthreads();

  for (int idx = tid; idx < 4 * OBS_; idx += 512) {
    const int g = idx >> 9, o = idx & 511;
    float acc = bd2[o];
    const float* w  = &Wd2[o * NG_];
    const float* tp = &t1[g * NG_];
#pragma unroll
    for (int k = 0; k < NG_; k += 4) {
      float4 tv = *(const float4*)(tp + k);
      float4 wv = *(const float4*)(w + k);
      acc = fmaf(tv.x, wv.x, acc); acc = fmaf(tv.y, wv.y, acc);
      acc = fmaf(tv.z, wv.z, acc); acc = fmaf(tv.w, wv.w, acc);
    }
    dbuf[idx] = tanhf(acc);
  }
  __syncthreads();

  {
    const int o = tid & 255, gg = tid >> 8;
    const float* w  = &Wf1[o * OBS_];
    const float* dA = &dbuf[(gg * 2 + 0) * OBS_];
    const float* dB = &dbuf[(gg * 2 + 1) * OBS_];
    float a0 = bf1[o], a1 = a0;
#pragma unroll 2
    for (int k = 0; k < OBS_; k += 4) {
      float4 wv = *(const float4*)(w + k);
      float4 xA = *(const float4*)(dA + k);
      float4 xB = *(const float4*)(dB + k);
      a0 = fmaf(xA.x, wv.x, a0); a0 = fmaf(xA.y, wv.y, a0);
      a0 = fmaf(xA.z, wv.z, a0); a0 = fmaf(xA.w, wv.w, a0);
      a1 = fmaf(xB.x, wv.x, a1); a1 = fmaf(xB.y, wv.y, a1);
      a1 = fmaf(xB.z, wv.z, a1); a1 = fmaf(xB.w, wv.w, a1);
    }
    f1b[(gg * 2 + 0) * 256 + o] = fmaxf(a0, 0.f);
    f1b[(gg * 2 + 1) * 256 + o] = fmaxf(a1, 0.f);
  }
  __syncthreads();

  {
    const int o = tid & 255, gg = tid >> 8;
    const float* w  = &Wf2[o * 256];
    const float* dA = &f1b[(gg * 2 + 0) * 256];
    const float* dB = &f1b[(gg * 2 + 1) * 256];
    float a0 = bf2[o], a1 = a0;
#pragma unroll 2
    for (int k = 0; k < 256; k += 4) {
      float4 wv = *(const float4*)(w + k);
      float4 xA = *(const float4*)(dA + k);
      float4 xB = *(const float4*)(dB + k);
      a0 = fmaf(xA.x, wv.x, a0); a0 = fmaf(xA.y, wv.y, a0);
      a0 = fmaf(xA.z, wv.z, a0); a0 = fmaf(xA.w, wv.w, a0);
      a1 = fmaf(xB.x, wv.x, a1); a1 = fmaf(xB.y, wv.y, a1);
      a1 = fmaf(xB.z, wv.z, a1); a1 = fmaf(xB.w, wv.w, a1);
    }
    f2b[(gg * 2 + 0) * 256 + o] = fmaxf(a0, 0.f);
    f2b[(gg * 2 + 1) * 256 + o] = fmaxf(a1, 0.f);
  }
  __syncthreads();

  if (tid < 16) {
    const int g  = tid >> 2;
    const int a  = (tid >> 1) & 1;
    const int hm = tid & 1;
    const float* fp = &f2b[g * 256];
    const float* w  = hm ? &Ws[a * 256] : &Wm[a * 256];
    float acc = hm ? bs[a] : bm[a];
    for (int k = 0; k < 256; ++k) acc = fmaf(fp[k], w[k], acc);
    if (hm == 0) out[(g0 + g) * 2 + a] = acc;
    else         out[2048 + (g0 + g) * 2 + a] = -5.0f + 3.5f * (tanhf(acc) + 1.0f);
  }
}

extern "C" void kernel_launch(void* const* d_in, const int* in_sizes, int n_in,
                              void* d_out, int out_size, void* d_ws, size_t ws_size,
                              hipStream_t stream) {
  const float* x     = (const float*)d_in[0];
  const int*   eidx  = (const int*)d_in[1];
  const float* eattr = (const float*)d_in[2];
  const float* Wl1 = (const float*)d_in[3];  const float* bl1 = (const float*)d_in[4];
  const float* Wr1 = (const float*)d_in[5];  const float* br1 = (const float*)d_in[6];
  const float* We1 = (const float*)d_in[7];  const float* att1= (const float*)d_in[8];
  const float* bc1 = (const float*)d_in[9];
  const float* Wl2 = (const float*)d_in[10]; const float* bl2 = (const float*)d_in[11];
  const float* Wr2 = (const float*)d_in[12]; const float* br2 = (const float*)d_in[13];
  const float* We2 = (const float*)d_in[14]; const float* att2= (const float*)d_in[15];
  const float* bc2 = (const float*)d_in[16];
  const float* Wd1 = (const float*)d_in[17]; const float* bd1 = (const float*)d_in[18];
  const float* Wd2 = (const float*)d_in[19]; const float* bd2 = (const float*)d_in[20];
  const float* Wf1 = (const float*)d_in[21]; const float* bf1 = (const float*)d_in[22];
  const float* Wf2 = (const float*)d_in[23]; const float* bf2 = (const float*)d_in[24];
  const float* Wm  = (const float*)d_in[25]; const float* bm  = (const float*)d_in[26];
  const float* Ws  = (const float*)d_in[27]; const float* bs  = (const float*)d_in[28];

  float* egoH = (float*)d_ws;   // [1024][160] fp32 = 640 KB

  gnn_two_layer_kernel<<<B_, 512, 0, stream>>>(
      x, eidx, eattr, Wl1, bl1, Wr1, br1, We1, att1, bc1,
      Wl2, bl2, Wr2, br2, We2, att2, bc2, egoH);

  mlp_head_kernel<<<B_ / 4, 512, 0, stream>>>(
      egoH, Wd1, bd1, Wd2, bd2, Wf1, bf1, Wf2, bf2, Wm, bm, Ws, bs,
      (float*)d_out);
}